// Round 9
// baseline (422.537 us; speedup 1.0000x reference)
//
#include <hip/hip_runtime.h>
#include <cstdint>

#define HIDDEN 128

typedef unsigned short u16;
using frag_t  = __attribute__((ext_vector_type(8))) short;   // 8 bf16 (4 VGPRs)
using f32x4_t = __attribute__((ext_vector_type(4))) float;   // MFMA accumulator

__device__ __forceinline__ float bf2f(u16 u) {
    union { unsigned int i; float f; } c;
    c.i = ((unsigned int)u) << 16;
    return c.f;
}
__device__ __forceinline__ u16 f2bf(float f) {
    unsigned int u = __float_as_uint(f);
    unsigned int r = (u + 0x7fffu + ((u >> 16) & 1u)) >> 16;   // RNE
    return (u16)r;
}

// ---------------- CSR build (edge_index arrives as int32 from harness) ----------------
// XCD-range partitioning: blocks with blockIdx&7==r own dst range [r*npr, (r+1)*npr).

__global__ void k_hist(const int* __restrict__ ei, int E, int* __restrict__ deg, int npr) {
    int r  = blockIdx.x & 7;
    int lo = r * npr, hi = lo + npr;
    int nb = gridDim.x >> 3;
    int bi = blockIdx.x >> 3;
    int tid = bi * blockDim.x + threadIdx.x;
    int stride = nb * blockDim.x;
    if ((E & 3) == 0) {
        const int4* d4 = (const int4*)(ei + E);
        int nch = E >> 2;
        for (int c = tid; c < nch; c += stride) {
            int4 d = d4[c];
            if (d.x >= lo && d.x < hi) atomicAdd(&deg[d.x], 1);
            if (d.y >= lo && d.y < hi) atomicAdd(&deg[d.y], 1);
            if (d.z >= lo && d.z < hi) atomicAdd(&deg[d.z], 1);
            if (d.w >= lo && d.w < hi) atomicAdd(&deg[d.w], 1);
        }
    } else {
        for (int e = tid; e < E; e += stride) {
            int d = ei[E + e];
            if (d >= lo && d < hi) atomicAdd(&deg[d], 1);
        }
    }
}

__global__ void k_scan1(const int* __restrict__ deg, int* __restrict__ rowp,
                        int* __restrict__ bsums, int n) {
    __shared__ int sh[1024];
    int t = threadIdx.x;
    int base = blockIdx.x * 1024;
    int v = (base + t < n) ? deg[base + t] : 0;
    sh[t] = v;
    __syncthreads();
    for (int off = 1; off < 1024; off <<= 1) {
        int x = sh[t];
        int y = (t >= off) ? sh[t - off] : 0;
        __syncthreads();
        sh[t] = x + y;
        __syncthreads();
    }
    if (base + t < n) rowp[base + t + 1] = sh[t];
    if (t == 1023) bsums[blockIdx.x] = sh[1023];
}

__global__ void k_scan2(int* __restrict__ bsums, int nb) {
    if (threadIdx.x == 0 && blockIdx.x == 0) {
        int run = 0;
        for (int b = 0; b < nb; ++b) { int v = bsums[b]; bsums[b] = run; run += v; }
    }
}

__global__ void k_scan3(int* __restrict__ rowp, const int* __restrict__ boffs,
                        int* __restrict__ fillp, int n) {
    int t = threadIdx.x;
    int b = blockIdx.x;
    int base = b * 1024;
    if (base + t < n) {
        int v = rowp[base + t + 1] + boffs[b];
        rowp[base + t + 1] = v;
        if (base + t + 1 < n) fillp[base + t + 1] = v;
    }
    if (b == 0 && t == 0) { rowp[0] = 0; fillp[0] = 0; }
}

__global__ void k_fill(const int* __restrict__ ei, int E,
                       int* __restrict__ fillpos, int* __restrict__ colx, int npr) {
    int r  = blockIdx.x & 7;
    int lo = r * npr, hi = lo + npr;
    int nb = gridDim.x >> 3;
    int bi = blockIdx.x >> 3;
    int tid = bi * blockDim.x + threadIdx.x;
    int stride = nb * blockDim.x;
    if ((E & 3) == 0) {
        const int4* s4 = (const int4*)ei;
        const int4* d4 = (const int4*)(ei + E);
        int nch = E >> 2;
        for (int c = tid; c < nch; c += stride) {
            int4 d = d4[c];
            bool m0 = d.x >= lo && d.x < hi;
            bool m1 = d.y >= lo && d.y < hi;
            bool m2 = d.z >= lo && d.z < hi;
            bool m3 = d.w >= lo && d.w < hi;
            if (m0 | m1 | m2 | m3) {
                int4 s = s4[c];
                if (m0) colx[atomicAdd(&fillpos[d.x], 1)] = s.x;
                if (m1) colx[atomicAdd(&fillpos[d.y], 1)] = s.y;
                if (m2) colx[atomicAdd(&fillpos[d.z], 1)] = s.z;
                if (m3) colx[atomicAdd(&fillpos[d.w], 1)] = s.w;
            }
        }
    } else {
        for (int e = tid; e < E; e += stride) {
            int d = ei[E + e];
            if (d >= lo && d < hi) colx[atomicAdd(&fillpos[d], 1)] = ei[e];
        }
    }
}

// ---------------- weight prep: transpose + split fp32 -> bf16 hi/lo, layout Wt[n][k] ----------------

__global__ void k_prep_w(const float* __restrict__ W_in,
                         const float* __restrict__ W_self,
                         const float* __restrict__ W_nbr,
                         u16* __restrict__ WtI_hi, u16* __restrict__ WtI_lo,
                         u16* __restrict__ WtS_hi, u16* __restrict__ WtS_lo,
                         u16* __restrict__ WtN_hi, u16* __restrict__ WtN_lo,
                         int L) {
    int idx = blockIdx.x * blockDim.x + threadIdx.x;
    int nIn = 64 * 128;
    int nSq = L * 128 * 128;
    float v; u16* phi; u16* plo; int o;
    if (idx < nIn) {
        int n = idx / 64, k = idx % 64;
        v = W_in[k * 128 + n]; phi = WtI_hi; plo = WtI_lo; o = n * 64 + k;
    } else if (idx < nIn + nSq) {
        int t = idx - nIn;
        int l = t / (128 * 128), r = t % (128 * 128);
        int n = r / 128, k = r % 128;
        v = W_self[l * 128 * 128 + k * 128 + n]; phi = WtS_hi; plo = WtS_lo;
        o = l * 128 * 128 + n * 128 + k;
    } else if (idx < nIn + 2 * nSq) {
        int t = idx - nIn - nSq;
        int l = t / (128 * 128), r = t % (128 * 128);
        int n = r / 128, k = r % 128;
        v = W_nbr[l * 128 * 128 + k * 128 + n]; phi = WtN_hi; plo = WtN_lo;
        o = l * 128 * 128 + n * 128 + k;
    } else return;
    u16 hi = f2bf(v);
    phi[o] = hi;
    plo[o] = f2bf(v - bf2f(hi));
}

__global__ void k_prep_x(const float* __restrict__ x, u16* __restrict__ xhi, int total) {
    int i = blockIdx.x * blockDim.x + threadIdx.x;
    int stride = gridDim.x * blockDim.x;
    for (; i < total; i += stride) xhi[i] = f2bf(x[i]);
}

// ---------------- aggregation: Sb_hi = bf16(mean over CSR row of hb_hi rows) ----------------

__global__ void k_agg(const ushort4* __restrict__ hb4, const int* __restrict__ rowp,
                      const int* __restrict__ colx, ushort4* __restrict__ Shi4, int n) {
    int g = (blockIdx.x * blockDim.x + threadIdx.x) >> 5;   // 32 lanes/node, lane = 4 cols
    int lane = threadIdx.x & 31;
    if (g >= n) return;
    int beg = rowp[g];
    int end = rowp[g + 1];
    float4 a0 = make_float4(0.f, 0.f, 0.f, 0.f);
    float4 a1 = a0, a2 = a0, a3 = a0;
    int e = beg;
    for (; e + 7 < end; e += 8) {
        int s0 = colx[e],     s1 = colx[e + 1], s2 = colx[e + 2], s3 = colx[e + 3];
        int s4 = colx[e + 4], s5 = colx[e + 5], s6 = colx[e + 6], s7 = colx[e + 7];
        ushort4 v0 = hb4[(size_t)s0 * 32 + lane];
        ushort4 v1 = hb4[(size_t)s1 * 32 + lane];
        ushort4 v2 = hb4[(size_t)s2 * 32 + lane];
        ushort4 v3 = hb4[(size_t)s3 * 32 + lane];
        ushort4 v4 = hb4[(size_t)s4 * 32 + lane];
        ushort4 v5 = hb4[(size_t)s5 * 32 + lane];
        ushort4 v6 = hb4[(size_t)s6 * 32 + lane];
        ushort4 v7 = hb4[(size_t)s7 * 32 + lane];
        a0.x += bf2f(v0.x); a0.y += bf2f(v0.y); a0.z += bf2f(v0.z); a0.w += bf2f(v0.w);
        a1.x += bf2f(v1.x); a1.y += bf2f(v1.y); a1.z += bf2f(v1.z); a1.w += bf2f(v1.w);
        a2.x += bf2f(v2.x); a2.y += bf2f(v2.y); a2.z += bf2f(v2.z); a2.w += bf2f(v2.w);
        a3.x += bf2f(v3.x); a3.y += bf2f(v3.y); a3.z += bf2f(v3.z); a3.w += bf2f(v3.w);
        a0.x += bf2f(v4.x); a0.y += bf2f(v4.y); a0.z += bf2f(v4.z); a0.w += bf2f(v4.w);
        a1.x += bf2f(v5.x); a1.y += bf2f(v5.y); a1.z += bf2f(v5.z); a1.w += bf2f(v5.w);
        a2.x += bf2f(v6.x); a2.y += bf2f(v6.y); a2.z += bf2f(v6.z); a2.w += bf2f(v6.w);
        a3.x += bf2f(v7.x); a3.y += bf2f(v7.y); a3.z += bf2f(v7.z); a3.w += bf2f(v7.w);
    }
    for (; e + 3 < end; e += 4) {
        int s0 = colx[e], s1 = colx[e + 1], s2 = colx[e + 2], s3 = colx[e + 3];
        ushort4 v0 = hb4[(size_t)s0 * 32 + lane];
        ushort4 v1 = hb4[(size_t)s1 * 32 + lane];
        ushort4 v2 = hb4[(size_t)s2 * 32 + lane];
        ushort4 v3 = hb4[(size_t)s3 * 32 + lane];
        a0.x += bf2f(v0.x); a0.y += bf2f(v0.y); a0.z += bf2f(v0.z); a0.w += bf2f(v0.w);
        a1.x += bf2f(v1.x); a1.y += bf2f(v1.y); a1.z += bf2f(v1.z); a1.w += bf2f(v1.w);
        a2.x += bf2f(v2.x); a2.y += bf2f(v2.y); a2.z += bf2f(v2.z); a2.w += bf2f(v2.w);
        a3.x += bf2f(v3.x); a3.y += bf2f(v3.y); a3.z += bf2f(v3.z); a3.w += bf2f(v3.w);
    }
    for (; e < end; ++e) {
        int s = colx[e];
        ushort4 v = hb4[(size_t)s * 32 + lane];
        a0.x += bf2f(v.x); a0.y += bf2f(v.y); a0.z += bf2f(v.z); a0.w += bf2f(v.w);
    }
    float acc[4];
    acc[0] = (a0.x + a1.x) + (a2.x + a3.x);
    acc[1] = (a0.y + a1.y) + (a2.y + a3.y);
    acc[2] = (a0.z + a1.z) + (a2.z + a3.z);
    acc[3] = (a0.w + a1.w) + (a2.w + a3.w);
    int deg = end - beg;
    float inv = 1.0f / (float)(deg > 1 ? deg : 1);
    ushort4 ohi;
    u16* ph = &ohi.x;
#pragma unroll
    for (int c = 0; c < 4; ++c) ph[c] = f2bf(acc[c] * inv);
    Shi4[(size_t)g * 32 + lane] = ohi;
}

// ---------------- MFMA GEMM, register-persistent weights, hoisted A loads ----------------
// n-group mapping: ng = (blockIdx>>3)&1 so the pair (b, b+8) covering the SAME A rows
// with different col-halves lands on the SAME XCD (blockIdx&7 = XCD) -> 2nd reader
// hits that XCD's L2 instead of refetching from HBM. mtb covers [0, grid/2) per ng.

template <int KF1, int KF2>
__global__ __launch_bounds__(256, 3) void k_gemm_mfma(
    const u16* __restrict__ A1h, const u16* __restrict__ A2h,
    const u16* __restrict__ B1h, const u16* __restrict__ B1l,
    const u16* __restrict__ B2h, const u16* __restrict__ B2l,
    const float* __restrict__ bias, float* __restrict__ C,
    u16* __restrict__ Hhi, int M, int do_elu)
{
    constexpr int K1 = KF1 * 32;
    constexpr int K2 = KF2 * 32;
    constexpr int KF = KF1 + KF2;
    int lane = threadIdx.x & 63;
    int w    = threadIdx.x >> 6;
    int m16  = lane & 15;
    int quad = lane >> 4;
    int kq   = quad * 8;
    int ng   = (blockIdx.x >> 3) & 1;
    int mtb  = (blockIdx.x & 7) | ((blockIdx.x >> 4) << 3);   // [0, gridDim/2)
    int ncol = (ng * 4 + w) * 16 + m16;     // this lane's output column (B row)

    // persistent B fragments (hi+lo), loaded once
    frag_t bh[KF], bl[KF];
    if (KF1) {
#pragma unroll
        for (int f = 0; f < KF1; ++f) {
            bh[f] = *(const frag_t*)&B1h[(size_t)ncol * K1 + f * 32 + kq];
            bl[f] = *(const frag_t*)&B1l[(size_t)ncol * K1 + f * 32 + kq];
        }
    }
    if (KF2) {
#pragma unroll
        for (int f = 0; f < KF2; ++f) {
            bh[KF1 + f] = *(const frag_t*)&B2h[(size_t)ncol * K2 + f * 32 + kq];
            bl[KF1 + f] = *(const frag_t*)&B2l[(size_t)ncol * K2 + f * 32 + kq];
        }
    }

    float bv = bias[ncol];
    int nMT  = (M + 31) >> 5;
    int step = gridDim.x >> 1;

    for (int mt = mtb; mt < nMT; mt += step) {
        int r0 = mt * 32 + m16;
        int r1 = r0 + 16;
        bool v0 = r0 < M, v1 = r1 < M;

        // hoisted A loads: all issue before any MFMA consumes them
        frag_t a0[KF], a1[KF];
        if (KF1) {
#pragma unroll
            for (int f = 0; f < KF1; ++f) {
                a0[f] = v0 ? *(const frag_t*)&A1h[(size_t)r0 * K1 + f * 32 + kq] : (frag_t){};
                a1[f] = v1 ? *(const frag_t*)&A1h[(size_t)r1 * K1 + f * 32 + kq] : (frag_t){};
            }
        }
        if (KF2) {
#pragma unroll
            for (int f = 0; f < KF2; ++f) {
                a0[KF1 + f] = v0 ? *(const frag_t*)&A2h[(size_t)r0 * K2 + f * 32 + kq] : (frag_t){};
                a1[KF1 + f] = v1 ? *(const frag_t*)&A2h[(size_t)r1 * K2 + f * 32 + kq] : (frag_t){};
            }
        }

        f32x4_t acc0 = (f32x4_t){0.f, 0.f, 0.f, 0.f};
        f32x4_t acc1 = (f32x4_t){0.f, 0.f, 0.f, 0.f};
#pragma unroll
        for (int f = 0; f < KF; ++f) {
            acc0 = __builtin_amdgcn_mfma_f32_16x16x32_bf16(a0[f], bh[f], acc0, 0, 0, 0);
            acc1 = __builtin_amdgcn_mfma_f32_16x16x32_bf16(a1[f], bh[f], acc1, 0, 0, 0);
            acc0 = __builtin_amdgcn_mfma_f32_16x16x32_bf16(a0[f], bl[f], acc0, 0, 0, 0);
            acc1 = __builtin_amdgcn_mfma_f32_16x16x32_bf16(a1[f], bl[f], acc1, 0, 0, 0);
        }

        // epilogue: C/D layout col = lane&15 (B side), row = quad*4 + reg (A side)
        int rb = mt * 32 + quad * 4;
#pragma unroll
        for (int r = 0; r < 4; ++r) {
            int row = rb + r;
            if (row < M) {
                float v = acc0[r] + bv;
                if (do_elu) v = (v > 0.f) ? v : expm1f(v);
                if (C) C[(size_t)row * HIDDEN + ncol] = v;
                if (Hhi) Hhi[(size_t)row * HIDDEN + ncol] = f2bf(v);
            }
            int row2 = row + 16;
            if (row2 < M) {
                float v = acc1[r] + bv;
                if (do_elu) v = (v > 0.f) ? v : expm1f(v);
                if (C) C[(size_t)row2 * HIDDEN + ncol] = v;
                if (Hhi) Hhi[(size_t)row2 * HIDDEN + ncol] = f2bf(v);
            }
        }
    }
}

// ---------------- launch ----------------

extern "C" void kernel_launch(void* const* d_in, const int* in_sizes, int n_in,
                              void* d_out, int out_size, void* d_ws, size_t ws_size,
                              hipStream_t stream) {
    const float* x        = (const float*)d_in[0];
    const int* ei         = (const int*)d_in[1];
    const float* W_in     = (const float*)d_in[2];
    const float* b_in     = (const float*)d_in[3];
    const float* W_self   = (const float*)d_in[4];
    const float* b_self   = (const float*)d_in[5];
    const float* W_nbr    = (const float*)d_in[6];
    float* out = (float*)d_out;

    const int IN_FEAT = 64;
    int N = in_sizes[0] / IN_FEAT;           // 50000
    int E = in_sizes[1] / 2;                 // 800000
    int L = in_sizes[4] / (HIDDEN * HIDDEN); // 3

    char* ws = (char*)d_ws;
    size_t off = 0;
    auto alloc = [&](size_t bytes) -> void* {
        void* p = ws + off;
        off = (off + bytes + 255) & ~(size_t)255;
        return p;
    };

    u16* hA_hi = (u16*)alloc((size_t)N * HIDDEN * 2);
    u16* hB_hi = (u16*)alloc((size_t)N * HIDDEN * 2);
    u16* xb_hi = (u16*)alloc((size_t)N * IN_FEAT * 2);
    u16* Sb_hi = (u16*)alloc((size_t)N * HIDDEN * 2);
    u16* WtI_hi = (u16*)alloc(128 * 64 * 2);
    u16* WtI_lo = (u16*)alloc(128 * 64 * 2);
    u16* WtS_hi = (u16*)alloc((size_t)L * 128 * 128 * 2);
    u16* WtS_lo = (u16*)alloc((size_t)L * 128 * 128 * 2);
    u16* WtN_hi = (u16*)alloc((size_t)L * 128 * 128 * 2);
    u16* WtN_lo = (u16*)alloc((size_t)L * 128 * 128 * 2);
    int* deg   = (int*)alloc((size_t)N * sizeof(int));
    int* rowp  = (int*)alloc((size_t)(N + 1) * sizeof(int));
    int* fillp = (int*)alloc((size_t)N * sizeof(int));
    int* colx  = (int*)alloc((size_t)E * sizeof(int));
    int* bsums = (int*)alloc(256 * sizeof(int));

    int npr = (N + 7) / 8;   // nodes per XCD range

    // CSR build (XCD-range-partitioned scatters)
    hipMemsetAsync(deg, 0, (size_t)N * sizeof(int), stream);
    k_hist<<<2048, 256, 0, stream>>>(ei, E, deg, npr);
    int nb = (N + 1023) / 1024;
    k_scan1<<<nb, 1024, 0, stream>>>(deg, rowp, bsums, N);
    k_scan2<<<1, 64, 0, stream>>>(bsums, nb);
    k_scan3<<<nb, 1024, 0, stream>>>(rowp, bsums, fillp, N);
    k_fill<<<2048, 256, 0, stream>>>(ei, E, fillp, colx, npr);

    // prep
    int wtot = 64 * 128 + 2 * L * 128 * 128;
    k_prep_w<<<(wtot + 255) / 256, 256, 0, stream>>>(W_in, W_self, W_nbr,
                                                     WtI_hi, WtI_lo, WtS_hi, WtS_lo,
                                                     WtN_hi, WtN_lo, L);
    k_prep_x<<<1024, 256, 0, stream>>>(x, xb_hi, N * IN_FEAT);

    const int GB = 3072;   // multiple of 16: ng = (b>>3)&1, XCD-paired

    // input projection: hA = bf16(x @ W_in + b_in)
    k_gemm_mfma<2, 0><<<GB, 256, 0, stream>>>(
        xb_hi, nullptr,
        WtI_hi, WtI_lo, nullptr, nullptr,
        b_in, nullptr, hA_hi, N, 0);

    u16* cur_hi = hA_hi;
    u16* nxt_hi = hB_hi;

    for (int l = 0; l < L; ++l) {
        k_agg<<<(N + 7) / 8, 256, 0, stream>>>((const ushort4*)cur_hi, rowp, colx,
                                               (ushort4*)Sb_hi, N);
        const u16* Wsh = WtS_hi + (size_t)l * 128 * 128;
        const u16* Wsl = WtS_lo + (size_t)l * 128 * 128;
        const u16* Wnh = WtN_hi + (size_t)l * 128 * 128;
        const u16* Wnl = WtN_lo + (size_t)l * 128 * 128;
        const float* bs = b_self + (size_t)l * HIDDEN;
        bool last = (l == L - 1);
        k_gemm_mfma<4, 4><<<GB, 256, 0, stream>>>(
            cur_hi, Sb_hi,
            Wsh, Wsl, Wnh, Wnl,
            bs, last ? out : nullptr,
            last ? nullptr : nxt_hi, N, 1);
        u16* t = cur_hi; cur_hi = nxt_hi; nxt_hi = t;
    }
}

// Round 10
// 356.643 us; speedup vs baseline: 1.1848x; 1.1848x over previous
//
#include <hip/hip_runtime.h>
#include <cstdint>

#define HIDDEN 128

typedef unsigned short u16;
using frag_t  = __attribute__((ext_vector_type(8))) short;   // 8 bf16 (4 VGPRs)
using f32x4_t = __attribute__((ext_vector_type(4))) float;   // MFMA accumulator

__device__ __forceinline__ float bf2f(u16 u) {
    union { unsigned int i; float f; } c;
    c.i = ((unsigned int)u) << 16;
    return c.f;
}
__device__ __forceinline__ u16 f2bf(float f) {
    unsigned int u = __float_as_uint(f);
    unsigned int r = (u + 0x7fffu + ((u >> 16) & 1u)) >> 16;   // RNE
    return (u16)r;
}

// fragment-major layout for MFMA A-operands: matrix [rows][K], KF = K/32.
// idx(row,col) = ((T*KF + f)*64 + q*16 + m)*8 + j ; T=row>>4, m=row&15,
// f=col>>5, q=(col&31)>>3, j=col&7. A wave's fragment load (rows 16T..16T+15,
// k-chunk f) is then base + lane*8 elements -> fully coalesced 1KB.
__device__ __forceinline__ size_t fmaj(int row, int col, int KF) {
    int T = row >> 4, m = row & 15;
    int f = col >> 5, q = (col & 31) >> 3, j = col & 7;
    return ((size_t)(T * KF + f) * 64 + q * 16 + m) * 8 + j;
}

// ---------------- CSR build (edge_index arrives as int32 from harness) ----------------
// XCD-range partitioning: blocks with blockIdx&7==r own dst range [r*npr, (r+1)*npr).

__global__ void k_hist(const int* __restrict__ ei, int E, int* __restrict__ deg, int npr) {
    int r  = blockIdx.x & 7;
    int lo = r * npr, hi = lo + npr;
    int nb = gridDim.x >> 3;
    int bi = blockIdx.x >> 3;
    int tid = bi * blockDim.x + threadIdx.x;
    int stride = nb * blockDim.x;
    if ((E & 3) == 0) {
        const int4* d4 = (const int4*)(ei + E);
        int nch = E >> 2;
        for (int c = tid; c < nch; c += stride) {
            int4 d = d4[c];
            if (d.x >= lo && d.x < hi) atomicAdd(&deg[d.x], 1);
            if (d.y >= lo && d.y < hi) atomicAdd(&deg[d.y], 1);
            if (d.z >= lo && d.z < hi) atomicAdd(&deg[d.z], 1);
            if (d.w >= lo && d.w < hi) atomicAdd(&deg[d.w], 1);
        }
    } else {
        for (int e = tid; e < E; e += stride) {
            int d = ei[E + e];
            if (d >= lo && d < hi) atomicAdd(&deg[d], 1);
        }
    }
}

__global__ void k_scan1(const int* __restrict__ deg, int* __restrict__ rowp,
                        int* __restrict__ bsums, int n) {
    __shared__ int sh[1024];
    int t = threadIdx.x;
    int base = blockIdx.x * 1024;
    int v = (base + t < n) ? deg[base + t] : 0;
    sh[t] = v;
    __syncthreads();
    for (int off = 1; off < 1024; off <<= 1) {
        int x = sh[t];
        int y = (t >= off) ? sh[t - off] : 0;
        __syncthreads();
        sh[t] = x + y;
        __syncthreads();
    }
    if (base + t < n) rowp[base + t + 1] = sh[t];
    if (t == 1023) bsums[blockIdx.x] = sh[1023];
}

__global__ void k_scan2(int* __restrict__ bsums, int nb) {
    if (threadIdx.x == 0 && blockIdx.x == 0) {
        int run = 0;
        for (int b = 0; b < nb; ++b) { int v = bsums[b]; bsums[b] = run; run += v; }
    }
}

__global__ void k_scan3(int* __restrict__ rowp, const int* __restrict__ boffs,
                        int* __restrict__ fillp, int n) {
    int t = threadIdx.x;
    int b = blockIdx.x;
    int base = b * 1024;
    if (base + t < n) {
        int v = rowp[base + t + 1] + boffs[b];
        rowp[base + t + 1] = v;
        if (base + t + 1 < n) fillp[base + t + 1] = v;
    }
    if (b == 0 && t == 0) { rowp[0] = 0; fillp[0] = 0; }
}

__global__ void k_fill(const int* __restrict__ ei, int E,
                       int* __restrict__ fillpos, int* __restrict__ colx, int npr) {
    int r  = blockIdx.x & 7;
    int lo = r * npr, hi = lo + npr;
    int nb = gridDim.x >> 3;
    int bi = blockIdx.x >> 3;
    int tid = bi * blockDim.x + threadIdx.x;
    int stride = nb * blockDim.x;
    if ((E & 3) == 0) {
        const int4* s4 = (const int4*)ei;
        const int4* d4 = (const int4*)(ei + E);
        int nch = E >> 2;
        for (int c = tid; c < nch; c += stride) {
            int4 d = d4[c];
            bool m0 = d.x >= lo && d.x < hi;
            bool m1 = d.y >= lo && d.y < hi;
            bool m2 = d.z >= lo && d.z < hi;
            bool m3 = d.w >= lo && d.w < hi;
            if (m0 | m1 | m2 | m3) {
                int4 s = s4[c];
                if (m0) colx[atomicAdd(&fillpos[d.x], 1)] = s.x;
                if (m1) colx[atomicAdd(&fillpos[d.y], 1)] = s.y;
                if (m2) colx[atomicAdd(&fillpos[d.z], 1)] = s.z;
                if (m3) colx[atomicAdd(&fillpos[d.w], 1)] = s.w;
            }
        }
    } else {
        for (int e = tid; e < E; e += stride) {
            int d = ei[E + e];
            if (d >= lo && d < hi) colx[atomicAdd(&fillpos[d], 1)] = ei[e];
        }
    }
}

// ---------------- weight prep: transpose + split fp32 -> bf16 hi/lo, layout Wt[n][k] ----------------

__global__ void k_prep_w(const float* __restrict__ W_in,
                         const float* __restrict__ W_self,
                         const float* __restrict__ W_nbr,
                         u16* __restrict__ WtI_hi, u16* __restrict__ WtI_lo,
                         u16* __restrict__ WtS_hi, u16* __restrict__ WtS_lo,
                         u16* __restrict__ WtN_hi, u16* __restrict__ WtN_lo,
                         int L) {
    int idx = blockIdx.x * blockDim.x + threadIdx.x;
    int nIn = 64 * 128;
    int nSq = L * 128 * 128;
    float v; u16* phi; u16* plo; int o;
    if (idx < nIn) {
        int n = idx / 64, k = idx % 64;
        v = W_in[k * 128 + n]; phi = WtI_hi; plo = WtI_lo; o = n * 64 + k;
    } else if (idx < nIn + nSq) {
        int t = idx - nIn;
        int l = t / (128 * 128), r = t % (128 * 128);
        int n = r / 128, k = r % 128;
        v = W_self[l * 128 * 128 + k * 128 + n]; phi = WtS_hi; plo = WtS_lo;
        o = l * 128 * 128 + n * 128 + k;
    } else if (idx < nIn + 2 * nSq) {
        int t = idx - nIn - nSq;
        int l = t / (128 * 128), r = t % (128 * 128);
        int n = r / 128, k = r % 128;
        v = W_nbr[l * 128 * 128 + k * 128 + n]; phi = WtN_hi; plo = WtN_lo;
        o = l * 128 * 128 + n * 128 + k;
    } else return;
    u16 hi = f2bf(v);
    phi[o] = hi;
    plo[o] = f2bf(v - bf2f(hi));
}

// x [N][64] fp32 -> fragment-major bf16 (KF=2)
__global__ void k_prep_x(const float* __restrict__ x, u16* __restrict__ xf, int total) {
    int i = blockIdx.x * blockDim.x + threadIdx.x;
    int stride = gridDim.x * blockDim.x;
    for (; i < total; i += stride) {
        int row = i >> 6, col = i & 63;
        xf[fmaj(row, col, 2)] = f2bf(x[i]);
    }
}

// ---------------- aggregation: Sf = bf16(mean over CSR row of hb rows), fragment-major out ----

__global__ void k_agg(const ushort4* __restrict__ hb4, const int* __restrict__ rowp,
                      const int* __restrict__ colx, u16* __restrict__ Sf, int n) {
    int g = (blockIdx.x * blockDim.x + threadIdx.x) >> 5;   // 32 lanes/node, lane = 4 cols
    int lane = threadIdx.x & 31;
    if (g >= n) return;
    int beg = rowp[g];
    int end = rowp[g + 1];
    float4 a0 = make_float4(0.f, 0.f, 0.f, 0.f);
    float4 a1 = a0, a2 = a0, a3 = a0;
    int e = beg;
    for (; e + 7 < end; e += 8) {
        int s0 = colx[e],     s1 = colx[e + 1], s2 = colx[e + 2], s3 = colx[e + 3];
        int s4 = colx[e + 4], s5 = colx[e + 5], s6 = colx[e + 6], s7 = colx[e + 7];
        ushort4 v0 = hb4[(size_t)s0 * 32 + lane];
        ushort4 v1 = hb4[(size_t)s1 * 32 + lane];
        ushort4 v2 = hb4[(size_t)s2 * 32 + lane];
        ushort4 v3 = hb4[(size_t)s3 * 32 + lane];
        ushort4 v4 = hb4[(size_t)s4 * 32 + lane];
        ushort4 v5 = hb4[(size_t)s5 * 32 + lane];
        ushort4 v6 = hb4[(size_t)s6 * 32 + lane];
        ushort4 v7 = hb4[(size_t)s7 * 32 + lane];
        a0.x += bf2f(v0.x); a0.y += bf2f(v0.y); a0.z += bf2f(v0.z); a0.w += bf2f(v0.w);
        a1.x += bf2f(v1.x); a1.y += bf2f(v1.y); a1.z += bf2f(v1.z); a1.w += bf2f(v1.w);
        a2.x += bf2f(v2.x); a2.y += bf2f(v2.y); a2.z += bf2f(v2.z); a2.w += bf2f(v2.w);
        a3.x += bf2f(v3.x); a3.y += bf2f(v3.y); a3.z += bf2f(v3.z); a3.w += bf2f(v3.w);
        a0.x += bf2f(v4.x); a0.y += bf2f(v4.y); a0.z += bf2f(v4.z); a0.w += bf2f(v4.w);
        a1.x += bf2f(v5.x); a1.y += bf2f(v5.y); a1.z += bf2f(v5.z); a1.w += bf2f(v5.w);
        a2.x += bf2f(v6.x); a2.y += bf2f(v6.y); a2.z += bf2f(v6.z); a2.w += bf2f(v6.w);
        a3.x += bf2f(v7.x); a3.y += bf2f(v7.y); a3.z += bf2f(v7.z); a3.w += bf2f(v7.w);
    }
    for (; e + 3 < end; e += 4) {
        int s0 = colx[e], s1 = colx[e + 1], s2 = colx[e + 2], s3 = colx[e + 3];
        ushort4 v0 = hb4[(size_t)s0 * 32 + lane];
        ushort4 v1 = hb4[(size_t)s1 * 32 + lane];
        ushort4 v2 = hb4[(size_t)s2 * 32 + lane];
        ushort4 v3 = hb4[(size_t)s3 * 32 + lane];
        a0.x += bf2f(v0.x); a0.y += bf2f(v0.y); a0.z += bf2f(v0.z); a0.w += bf2f(v0.w);
        a1.x += bf2f(v1.x); a1.y += bf2f(v1.y); a1.z += bf2f(v1.z); a1.w += bf2f(v1.w);
        a2.x += bf2f(v2.x); a2.y += bf2f(v2.y); a2.z += bf2f(v2.z); a2.w += bf2f(v2.w);
        a3.x += bf2f(v3.x); a3.y += bf2f(v3.y); a3.z += bf2f(v3.z); a3.w += bf2f(v3.w);
    }
    for (; e < end; ++e) {
        int s = colx[e];
        ushort4 v = hb4[(size_t)s * 32 + lane];
        a0.x += bf2f(v.x); a0.y += bf2f(v.y); a0.z += bf2f(v.z); a0.w += bf2f(v.w);
    }
    float acc[4];
    acc[0] = (a0.x + a1.x) + (a2.x + a3.x);
    acc[1] = (a0.y + a1.y) + (a2.y + a3.y);
    acc[2] = (a0.z + a1.z) + (a2.z + a3.z);
    acc[3] = (a0.w + a1.w) + (a2.w + a3.w);
    int deg = end - beg;
    float inv = 1.0f / (float)(deg > 1 ? deg : 1);
    ushort4 ohi;
    u16* ph = &ohi.x;
#pragma unroll
    for (int c = 0; c < 4; ++c) ph[c] = f2bf(acc[c] * inv);
    // fragment-major store (KF=4): cols lane*4..lane*4+3 share one (f,q,j-range) group
    int T = g >> 4, m = g & 15;
    int f = lane >> 3;
    int q = (lane & 7) >> 1;
    int jo = (lane & 1) * 4;
    *(ushort4*)&Sf[((size_t)(T * 4 + f) * 64 + q * 16 + m) * 8 + jo] = ohi;
}

// ---------------- MFMA GEMM: frag-major A (coalesced 1KB loads), register-persistent B ----
// ng = (blockIdx>>3)&1 : XCD-paired col-halves share A rows in L2.

template <int KF1, int KF2>
__global__ __launch_bounds__(256, 2) void k_gemm_mfma(
    const u16* __restrict__ A1f, const u16* __restrict__ A2f,
    const u16* __restrict__ B1h, const u16* __restrict__ B1l,
    const u16* __restrict__ B2h, const u16* __restrict__ B2l,
    const float* __restrict__ bias, float* __restrict__ C,
    u16* __restrict__ Hrow, u16* __restrict__ Hf,
    int M, int do_elu)
{
    constexpr int K1 = KF1 * 32;
    constexpr int K2 = KF2 * 32;
    constexpr int KF = KF1 + KF2;
    int lane = threadIdx.x & 63;
    int w    = threadIdx.x >> 6;
    int m16  = lane & 15;
    int quad = lane >> 4;
    int kq   = quad * 8;
    int ng   = (blockIdx.x >> 3) & 1;
    int mtb  = (blockIdx.x & 7) | ((blockIdx.x >> 4) << 3);   // [0, gridDim/2)
    int ncol = (ng * 4 + w) * 16 + m16;     // this lane's output column (B row)

    // persistent B fragments (hi+lo), loaded once
    frag_t bh[KF], bl[KF];
    if (KF1) {
#pragma unroll
        for (int f = 0; f < KF1; ++f) {
            bh[f] = *(const frag_t*)&B1h[(size_t)ncol * K1 + f * 32 + kq];
            bl[f] = *(const frag_t*)&B1l[(size_t)ncol * K1 + f * 32 + kq];
        }
    }
    if (KF2) {
#pragma unroll
        for (int f = 0; f < KF2; ++f) {
            bh[KF1 + f] = *(const frag_t*)&B2h[(size_t)ncol * K2 + f * 32 + kq];
            bl[KF1 + f] = *(const frag_t*)&B2l[(size_t)ncol * K2 + f * 32 + kq];
        }
    }

    float bv = bias[ncol];
    int nMT  = (M + 31) >> 5;
    int step = gridDim.x >> 1;
    int fcol = ncol >> 5;            // Hf store coords (KFout = 4)
    int qcol = (ncol & 31) >> 3;
    int jcol = ncol & 7;

    for (int mt = mtb; mt < nMT; mt += step) {
        int T0 = mt * 2, T1 = T0 + 1;   // 16-row sub-tiles (padded alloc: no guards)

        // coalesced A loads: base + lane*8 elements (1KB per wave-load)
        frag_t a0[KF], a1[KF];
        if (KF1) {
#pragma unroll
            for (int f = 0; f < KF1; ++f) {
                a0[f] = *(const frag_t*)&A1f[((size_t)(T0 * KF1 + f) * 64 + lane) * 8];
                a1[f] = *(const frag_t*)&A1f[((size_t)(T1 * KF1 + f) * 64 + lane) * 8];
            }
        }
        if (KF2) {
#pragma unroll
            for (int f = 0; f < KF2; ++f) {
                a0[KF1 + f] = *(const frag_t*)&A2f[((size_t)(T0 * KF2 + f) * 64 + lane) * 8];
                a1[KF1 + f] = *(const frag_t*)&A2f[((size_t)(T1 * KF2 + f) * 64 + lane) * 8];
            }
        }

        f32x4_t acc0 = (f32x4_t){0.f, 0.f, 0.f, 0.f};
        f32x4_t acc1 = (f32x4_t){0.f, 0.f, 0.f, 0.f};
#pragma unroll
        for (int f = 0; f < KF; ++f) {
            acc0 = __builtin_amdgcn_mfma_f32_16x16x32_bf16(a0[f], bh[f], acc0, 0, 0, 0);
            acc1 = __builtin_amdgcn_mfma_f32_16x16x32_bf16(a1[f], bh[f], acc1, 0, 0, 0);
            acc0 = __builtin_amdgcn_mfma_f32_16x16x32_bf16(a0[f], bl[f], acc0, 0, 0, 0);
            acc1 = __builtin_amdgcn_mfma_f32_16x16x32_bf16(a1[f], bl[f], acc1, 0, 0, 0);
        }

        // epilogue: C/D layout col = lane&15, row = quad*4 + reg
        int rb = mt * 32 + quad * 4;
#pragma unroll
        for (int r = 0; r < 4; ++r) {
#pragma unroll
            for (int half = 0; half < 2; ++half) {
                int row = rb + r + half * 16;
                float av = half ? acc1[r] : acc0[r];
                if (row < M) {
                    float v = av + bv;
                    if (do_elu) v = (v > 0.f) ? v : expm1f(v);
                    if (C) C[(size_t)row * HIDDEN + ncol] = v;
                    if (Hrow) {
                        u16 hv = f2bf(v);
                        Hrow[(size_t)row * HIDDEN + ncol] = hv;
                        Hf[((size_t)((row >> 4) * 4 + fcol) * 64 + qcol * 16 + (row & 15)) * 8 + jcol] = hv;
                    }
                }
            }
        }
    }
}

// ---------------- launch ----------------

extern "C" void kernel_launch(void* const* d_in, const int* in_sizes, int n_in,
                              void* d_out, int out_size, void* d_ws, size_t ws_size,
                              hipStream_t stream) {
    const float* x        = (const float*)d_in[0];
    const int* ei         = (const int*)d_in[1];
    const float* W_in     = (const float*)d_in[2];
    const float* b_in     = (const float*)d_in[3];
    const float* W_self   = (const float*)d_in[4];
    const float* b_self   = (const float*)d_in[5];
    const float* W_nbr    = (const float*)d_in[6];
    float* out = (float*)d_out;

    const int IN_FEAT = 64;
    int N = in_sizes[0] / IN_FEAT;           // 50000
    int E = in_sizes[1] / 2;                 // 800000
    int L = in_sizes[4] / (HIDDEN * HIDDEN); // 3

    char* ws = (char*)d_ws;
    size_t off = 0;
    auto alloc = [&](size_t bytes) -> void* {
        void* p = ws + off;
        off = (off + bytes + 255) & ~(size_t)255;
        return p;
    };

    int nT = ((N + 31) / 32) * 2;            // 16-row tiles, padded to macro-tile pairs

    u16* hRowA = (u16*)alloc((size_t)N * HIDDEN * 2);
    u16* hRowB = (u16*)alloc((size_t)N * HIDDEN * 2);
    u16* hfA   = (u16*)alloc((size_t)nT * 4 * 64 * 8 * 2);   // KF=4 frag-major
    u16* hfB   = (u16*)alloc((size_t)nT * 4 * 64 * 8 * 2);
    u16* xf    = (u16*)alloc((size_t)nT * 2 * 64 * 8 * 2);   // KF=2
    u16* Sf    = (u16*)alloc((size_t)nT * 4 * 64 * 8 * 2);
    u16* WtI_hi = (u16*)alloc(128 * 64 * 2);
    u16* WtI_lo = (u16*)alloc(128 * 64 * 2);
    u16* WtS_hi = (u16*)alloc((size_t)L * 128 * 128 * 2);
    u16* WtS_lo = (u16*)alloc((size_t)L * 128 * 128 * 2);
    u16* WtN_hi = (u16*)alloc((size_t)L * 128 * 128 * 2);
    u16* WtN_lo = (u16*)alloc((size_t)L * 128 * 128 * 2);
    int* deg   = (int*)alloc((size_t)N * sizeof(int));
    int* rowp  = (int*)alloc((size_t)(N + 1) * sizeof(int));
    int* fillp = (int*)alloc((size_t)N * sizeof(int));
    int* colx  = (int*)alloc((size_t)E * sizeof(int));
    int* bsums = (int*)alloc(256 * sizeof(int));

    int npr = (N + 7) / 8;   // nodes per XCD range

    // CSR build (XCD-range-partitioned scatters)
    hipMemsetAsync(deg, 0, (size_t)N * sizeof(int), stream);
    k_hist<<<2048, 256, 0, stream>>>(ei, E, deg, npr);
    int nb = (N + 1023) / 1024;
    k_scan1<<<nb, 1024, 0, stream>>>(deg, rowp, bsums, N);
    k_scan2<<<1, 64, 0, stream>>>(bsums, nb);
    k_scan3<<<nb, 1024, 0, stream>>>(rowp, bsums, fillp, N);
    k_fill<<<2048, 256, 0, stream>>>(ei, E, fillp, colx, npr);

    // prep
    int wtot = 64 * 128 + 2 * L * 128 * 128;
    k_prep_w<<<(wtot + 255) / 256, 256, 0, stream>>>(W_in, W_self, W_nbr,
                                                     WtI_hi, WtI_lo, WtS_hi, WtS_lo,
                                                     WtN_hi, WtN_lo, L);
    k_prep_x<<<1024, 256, 0, stream>>>(x, xf, N * IN_FEAT);

    const int GB = 1536;   // multiple of 16: ng=(b>>3)&1 XCD-paired, 2+ tiles/block

    // input projection: h = bf16(x @ W_in + b_in)  -> hRowA + hfA
    k_gemm_mfma<2, 0><<<GB, 256, 0, stream>>>(
        xf, nullptr,
        WtI_hi, WtI_lo, nullptr, nullptr,
        b_in, nullptr, hRowA, hfA, N, 0);

    u16* curRow = hRowA; u16* curF = hfA;
    u16* nxtRow = hRowB; u16* nxtF = hfB;

    for (int l = 0; l < L; ++l) {
        k_agg<<<(N + 7) / 8, 256, 0, stream>>>((const ushort4*)curRow, rowp, colx, Sf, N);
        const u16* Wsh = WtS_hi + (size_t)l * 128 * 128;
        const u16* Wsl = WtS_lo + (size_t)l * 128 * 128;
        const u16* Wnh = WtN_hi + (size_t)l * 128 * 128;
        const u16* Wnl = WtN_lo + (size_t)l * 128 * 128;
        const float* bs = b_self + (size_t)l * HIDDEN;
        bool last = (l == L - 1);
        k_gemm_mfma<4, 4><<<GB, 256, 0, stream>>>(
            curF, Sf,
            Wsh, Wsl, Wnh, Wnl,
            bs, last ? out : nullptr,
            last ? nullptr : nxtRow, last ? nullptr : nxtF, N, 1);
        u16* tr = curRow; curRow = nxtRow; nxtRow = tr;
        u16* tf = curF;   curF = nxtF;     nxtF = tf;
    }
}